// Round 11
// baseline (945.816 us; speedup 1.0000x reference)
//
#include <hip/hip_runtime.h>
#include <stdint.h>

typedef uint16_t u16;
typedef short short8 __attribute__((ext_vector_type(8)));
typedef float f32x4 __attribute__((ext_vector_type(4)));

__device__ __forceinline__ u16 f2bf(float f){
  uint32_t u = __float_as_uint(f);
  u += 0x7fff + ((u >> 16) & 1);   // RNE
  return (u16)(u >> 16);
}

__device__ __forceinline__ void gload_lds16(const u16* g, const char* l){
  __builtin_amdgcn_global_load_lds((const __attribute__((address_space(1))) void*)g,
                                   (__attribute__((address_space(3))) void*)l,
                                   16, 0, 0);
}

// ---- prep: fused fp32 -> bf16 cast of x, W1, W2 (8 elems/thread/iter) ----
__global__ void cast3_kernel(const float* __restrict__ x, const float* __restrict__ W1,
                             const float* __restrict__ W2, u16* __restrict__ xb,
                             u16* __restrict__ W1b, u16* __restrict__ W2b){
  long i = (long)blockIdx.x * blockDim.x + threadIdx.x;
  long stride = (long)gridDim.x * blockDim.x;
  for (; i < 8388608L; i += stride){
    const float* s; u16* d; long off;
    if (i < 4194304L){ s = x;  d = xb;  off = i; }
    else if (i < 6291456L){ s = W1; d = W1b; off = i - 4194304L; }
    else { s = W2; d = W2b; off = i - 6291456L; }
    float4 a = *(const float4*)(s + off*8);
    float4 b = *(const float4*)(s + off*8 + 4);
    u16 r[8] = {f2bf(a.x), f2bf(a.y), f2bf(a.z), f2bf(a.w),
                f2bf(b.x), f2bf(b.y), f2bf(b.z), f2bf(b.w)};
    *(uint4*)(d + off*8) = *(const uint4*)r;
  }
}

// ---- prep: L = tril(pre) cast to bf16 ; layout (n,u,v) 8x512x512 ----
__global__ void mask_cast_L_kernel(const float* __restrict__ pre, u16* __restrict__ L){
  long i = (long)blockIdx.x * blockDim.x + threadIdx.x;  // chunk of 8 along v
  if (i >= 8L*512*64) return;
  int v0 = (int)(i & 63) * 8;
  int u  = (int)((i >> 6) & 511);
  float4 a = *(const float4*)(pre + i*8);
  float4 b = *(const float4*)(pre + i*8 + 4);
  float vals[8] = {a.x,a.y,a.z,a.w,b.x,b.y,b.z,b.w};
  u16 r[8];
  #pragma unroll
  for (int j=0;j<8;j++) r[j] = f2bf((v0 + j <= u) ? vals[j] : 0.0f);
  *(uint4*)(L + i*8) = *(const uint4*)r;
}

// ---- read-ahead pipelined NT GEMM: C[M,N] = A(MxK,rm) * B(NxK,rm)^T ----
// 256x256 tile, BK=32, 8 waves (2Mx4N), wave 128x64, acc[8][4] f32x4.
// 4 LDS buffers (32KB), stage 3 ahead, counted vmcnt(4), one barrier/K-tile.
// READ-AHEAD with FULL double frag sets: body(j) = {12 ds_reads of tile j+1
// (set Q) + stage(j+3)} -> sched_barrier -> 32 MFMA on set P (operands read
// one body ago, lgkm long satisfied) -> vmcnt(4) + barrier. LDS services
// reads(j+1) WHILE matrix pipes run MFMA(j) -> pipes overlap.
// Swizzle g(r)=(r>>1)&3 on 16B chunks, both-sides (0 conflicts, verified r4).
// tri: 1 = early-return blocks above diagonal (S-gemm; output unread
// downstream); 2 = Keff=row0+256 (O-gemm, A lower-tri).
// EPI: 0 bf16; 1 +bias[row] bf16; 2 tril*scale bf16; 3 +bias[col] fp32.
template<int EPI>
__global__ __launch_bounds__(512, 1)
void gemm_nt3(const u16* __restrict__ A, const u16* __restrict__ B,
              void* __restrict__ Cv, int K, int lda, int ldb, int ldc,
              long asb, long asn, long bsb, long bsn, long csb, long csn,
              const float* __restrict__ bias, float scale, int tri)
{
  extern __shared__ __align__(16) char smem[];   // 4 * 32768 = 131072 B
  const int t = threadIdx.x;
  const int lane = t & 63;
  const int wave = t >> 6;          // 0..7
  const int wm = wave >> 2;         // 0..1
  const int wn = wave & 3;          // 0..3
  const long zb = blockIdx.z >> 3, zn = blockIdx.z & 7;
  A += zb*asb + zn*asn;
  B += zb*bsb + zn*bsn;
  const int row0 = blockIdx.y * 256, col0 = blockIdx.x * 256;

  if (tri == 1 && col0 >= row0 + 256) return;   // block-uniform, pre-barrier

  const int l15 = lane & 15, l4 = lane >> 4;

  // staging: thread t -> LDS slot t (16B), row = t>>2, chunk pos = t&3;
  // source chunk pre-swizzled: c_g = pos ^ g(row), g(r) = (r>>1)&3
  const int srow = t >> 2;                                // 0..127
  const int scol = (((t & 3) ^ ((srow >> 1) & 3)) * 8);   // elements
  const u16* gA = A + (long)(row0 + srow)*lda + scol;
  const u16* gB = B + (long)(col0 + srow)*ldb + scol;
  const long a128 = 128L*(long)lda, b128 = 128L*(long)ldb;
  const int ldst = t * 16;                                // byte slot

  // ds_read swizzled chunk: pos = l4 ^ g(row), g from l15
  const int csw = (l4 ^ ((l15 >> 1) & 3)) * 16;
  const int raw = (wm*128 + l15)*64 + csw;          // A read base (bytes)
  const int rbw = 16384 + (wn*64 + l15)*64 + csw;   // B read base

  f32x4 acc[8][4];
  #pragma unroll
  for (int m=0;m<8;m++)
    #pragma unroll
    for (int n=0;n<4;n++) acc[m][n] = (f32x4){0.f,0.f,0.f,0.f};

  int Keff = K;
  if (tri == 2) Keff = (row0 + 256 < K) ? (row0 + 256) : K;
  const int NT = Keff >> 5;   // 8 / 16 / 128 (multiple of 4)

  short8 afr[2][8], bfr[2][4];   // double fragment sets (static indices only)

#define STG(PA, PB, BUF) \
  gload_lds16((PA),        smem + (BUF)*32768 +         ldst); \
  gload_lds16((PA) + a128, smem + (BUF)*32768 +  8192 + ldst); \
  gload_lds16((PB),        smem + (BUF)*32768 + 16384 + ldst); \
  gload_lds16((PB) + b128, smem + (BUF)*32768 + 24576 + ldst);

#define RDS(S, BUF) { \
  const char* b_ = smem + (BUF)*32768; \
  _Pragma("unroll") \
  for (int n=0;n<4;n++) bfr[S][n] = *(const short8*)(b_ + rbw + n*1024); \
  _Pragma("unroll") \
  for (int m=0;m<8;m++) afr[S][m] = *(const short8*)(b_ + raw + m*1024); }

#define MM(S) { \
  __builtin_amdgcn_s_setprio(1); \
  _Pragma("unroll") \
  for (int m=0;m<8;m++) \
    _Pragma("unroll") \
    for (int n=0;n<4;n++) \
      acc[m][n] = __builtin_amdgcn_mfma_f32_16x16x32_bf16(afr[S][m], bfr[S][n], acc[m][n],0,0,0); \
  __builtin_amdgcn_s_setprio(0); }

#define ENDB(VMS) \
  asm volatile("s_waitcnt vmcnt(" VMS ")" ::: "memory"); \
  __builtin_amdgcn_s_barrier(); \
  asm volatile("" ::: "memory");

// body(j): P=j&1, Q=1-P, NXT=(j+1)&3, stage buf (j+3)&3
#define BODY(P, Q, NXT, DOST, PA, PB, VMS) { \
  RDS(Q, NXT) \
  if (DOST){ STG(PA, PB, ((NXT)+2)&3) } \
  __builtin_amdgcn_sched_barrier(0); \
  MM(P) \
  ENDB(VMS) }

  // prologue: stage tiles 0,1,2; tiles 0 AND 1 landed (body0 reads tile 1);
  // preload frags(0) into set 0.
  STG(gA,      gB,      0)
  STG(gA + 32, gB + 32, 1)
  STG(gA + 64, gB + 64, 2)
  asm volatile("s_waitcnt vmcnt(4)" ::: "memory");
  __builtin_amdgcn_s_barrier();
  asm volatile("" ::: "memory");
  RDS(0, 0)

  // main: bodies j = tb..tb+3 (buffers 0..3); body(j) stages tile j+3
  #pragma unroll 1
  for (int tb = 0; tb < NT - 4; tb += 4){
    const u16* pa = gA + (long)(tb + 3)*32;
    const u16* pb = gB + (long)(tb + 3)*32;
    BODY(0, 1, 1, true, pa,      pb,      "4")
    BODY(1, 0, 2, true, pa + 32, pb + 32, "4")
    BODY(0, 1, 3, true, pa + 64, pb + 64, "4")
    BODY(1, 0, 0, true, pa + 96, pb + 96, "4")
  }
  // tail: bodies NT-4..NT-1 (buffers 0..3); one last stage (tile NT-1)
  {
    const u16* pa = gA + (long)(NT - 1)*32;
    const u16* pb = gB + (long)(NT - 1)*32;
    BODY(0, 1, 1, true,  pa, pb, "4")   // j=NT-4: reads NT-3, stages NT-1
    BODY(1, 0, 2, false, pa, pb, "0")   // j=NT-3: reads NT-2, drain all
    BODY(0, 1, 3, false, pa, pb, "0")   // j=NT-2: reads NT-1
    MM(1)                                // j=NT-1: compute only
  }
#undef STG
#undef RDS
#undef MM
#undef ENDB
#undef BODY

  // epilogue: C/D map col=lane&15, row=(lane>>4)*4+g  (HW-verified)
  if constexpr (EPI == 3){
    float* C = (float*)Cv;
    #pragma unroll
    for (int m=0;m<8;m++){
      int r0 = row0 + wm*128 + m*16 + l4*4;
      #pragma unroll
      for (int n=0;n<4;n++){
        int c = col0 + wn*64 + n*16 + l15;
        float bc = bias[c];
        #pragma unroll
        for (int g=0; g<4; g++)
          C[(long)(r0+g)*ldc + c] = acc[m][n][g] + bc;
      }
    }
  } else {
    u16* C = (u16*)Cv + zb*csb + zn*csn;
    #pragma unroll
    for (int m=0;m<8;m++){
      int r0 = row0 + wm*128 + m*16 + l4*4;
      #pragma unroll
      for (int n=0;n<4;n++){
        int c = col0 + wn*64 + n*16 + l15;
        #pragma unroll
        for (int g=0;g<4;g++){
          float v = acc[m][n][g];
          int r = r0 + g;
          if constexpr (EPI==1) v += bias[r];
          if constexpr (EPI==2) v = (c <= r) ? v*scale : 0.0f;
          C[(long)r*ldc + c] = f2bf(v);
        }
      }
    }
  }
}

// Workspace layout (bytes):
//   xb   @ 0          : 8192x4096 bf16
//   W1b  @ 67108864   : 4096x4096 bf16
//   W2b  @ 100663296  : 4096x4096 bf16
//   Lb   @ 134217728  : 8x512x512 bf16
//   Mb   @ 138412032  : 8x512x512 bf16
//   PtG  @ 142606336  : 4096x8192 bf16   PtG[c][r] = P_full[r][c]
//   MPt  @ 209715200  : 128x512x512 bf16 MPt[z][j][u] = MP[b,n,u,j]
//   Sb   @ 276824064  : 128x512x512 bf16
//   Ob   = MPt (reuse; MPt dead after S-gemm)

#define LDSB 131072

extern "C" void kernel_launch(void* const* d_in, const int* in_sizes, int n_in,
                              void* d_out, int out_size, void* d_ws, size_t ws_size,
                              hipStream_t stream)
{
  (void)in_sizes; (void)n_in; (void)out_size; (void)ws_size;
  const float* x   = (const float*)d_in[0];
  const float* W1  = (const float*)d_in[1];
  const float* b1  = (const float*)d_in[2];
  const float* pre = (const float*)d_in[3];
  const float* W2  = (const float*)d_in[4];
  const float* b2  = (const float*)d_in[5];
  float* out = (float*)d_out;
  char* ws = (char*)d_ws;

  u16* xb  = (u16*)(ws + 0L);
  u16* W1b = (u16*)(ws + 67108864L);
  u16* W2b = (u16*)(ws + 100663296L);
  u16* Lb  = (u16*)(ws + 134217728L);
  u16* Mb  = (u16*)(ws + 138412032L);
  u16* Pt  = (u16*)(ws + 142606336L);
  u16* MPt = (u16*)(ws + 209715200L);
  u16* Sb  = (u16*)(ws + 276824064L);
  u16* Ob  = MPt;  // reuse: MPt consumed by S-gemm before O-gemm writes

  hipFuncSetAttribute((const void*)gemm_nt3<0>, hipFuncAttributeMaxDynamicSharedMemorySize, LDSB);
  hipFuncSetAttribute((const void*)gemm_nt3<1>, hipFuncAttributeMaxDynamicSharedMemorySize, LDSB);
  hipFuncSetAttribute((const void*)gemm_nt3<2>, hipFuncAttributeMaxDynamicSharedMemorySize, LDSB);
  hipFuncSetAttribute((const void*)gemm_nt3<3>, hipFuncAttributeMaxDynamicSharedMemorySize, LDSB);

  // preps
  cast3_kernel<<<4096,256,0,stream>>>(x, W1, W2, xb, W1b, W2b);
  mask_cast_L_kernel<<<1024,256,0,stream>>>(pre, Lb);

  // M[n] = L[n] ·NT· L[n]          (8 batches, 512^3)
  gemm_nt3<0><<<dim3(2,2,8),512,LDSB,stream>>>(Lb, Lb, Mb, 512, 512,512,512,
      0, 262144, 0, 262144, 0, 262144, nullptr, 0.f, 0);

  // PtG = W1b ·NT· xb + b1[row]    (4096 x 8192, K=4096)
  gemm_nt3<1><<<dim3(32,16,1),512,LDSB,stream>>>(W1b, xb, Pt, 4096, 4096,4096,8192,
      0,0, 0,0, 0,0, b1, 0.f, 0);

  // MPt[z] = Pt(b,n) ·NT· M[n]     (128 batches, 512^3)
  gemm_nt3<0><<<dim3(2,2,128),512,LDSB,stream>>>(Pt, Mb, MPt, 512, 8192,512,512,
      512, 512L*8192, 0, 262144, 8L*262144, 262144, nullptr, 0.f, 0);

  // S[z] = Pt(b,n) ·NT· MPt[z], *1/sqrt(512), tril mask; skip upper blocks
  gemm_nt3<2><<<dim3(2,2,128),512,LDSB,stream>>>(Pt, MPt, Sb, 512, 8192,512,512,
      512, 512L*8192, 8L*262144, 262144, 8L*262144, 262144, nullptr, 0.04419417382f, 1);

  // O(b,n) = S[z] ·NT· Pt(b,n) -> Ob; S lower-tri => Keff = row0+256
  gemm_nt3<0><<<dim3(2,2,128),512,LDSB,stream>>>(Sb, Pt, Ob, 512, 512,8192,4096,
      8L*262144, 262144, 512, 512L*8192, 512L*4096, 512, nullptr, 0.f, 2);

  // Y = Ob ·NT· W2b + b2[col]      (8192 x 4096, K=4096, fp32 out)
  gemm_nt3<3><<<dim3(16,32,1),512,LDSB,stream>>>(Ob, W2b, out, 4096, 4096,4096,4096,
      0,0, 0,0, 0,0, b2, 0.f, 0);
}

// Round 12
// 703.170 us; speedup vs baseline: 1.3451x; 1.3451x over previous
//
#include <hip/hip_runtime.h>
#include <stdint.h>

typedef uint16_t u16;
typedef short short8 __attribute__((ext_vector_type(8)));
typedef float f32x4 __attribute__((ext_vector_type(4)));

__device__ __forceinline__ u16 f2bf(float f){
  uint32_t u = __float_as_uint(f);
  u += 0x7fff + ((u >> 16) & 1);   // RNE
  return (u16)(u >> 16);
}

__device__ __forceinline__ void gload_lds16(const u16* g, const char* l){
  __builtin_amdgcn_global_load_lds((const __attribute__((address_space(1))) void*)g,
                                   (__attribute__((address_space(3))) void*)l,
                                   16, 0, 0);
}

// ---- prep: fused fp32 -> bf16 cast of x, W1, W2 (8 elems/thread/iter) ----
__global__ void cast3_kernel(const float* __restrict__ x, const float* __restrict__ W1,
                             const float* __restrict__ W2, u16* __restrict__ xb,
                             u16* __restrict__ W1b, u16* __restrict__ W2b){
  long i = (long)blockIdx.x * blockDim.x + threadIdx.x;
  long stride = (long)gridDim.x * blockDim.x;
  for (; i < 8388608L; i += stride){
    const float* s; u16* d; long off;
    if (i < 4194304L){ s = x;  d = xb;  off = i; }
    else if (i < 6291456L){ s = W1; d = W1b; off = i - 4194304L; }
    else { s = W2; d = W2b; off = i - 6291456L; }
    float4 a = *(const float4*)(s + off*8);
    float4 b = *(const float4*)(s + off*8 + 4);
    u16 r[8] = {f2bf(a.x), f2bf(a.y), f2bf(a.z), f2bf(a.w),
                f2bf(b.x), f2bf(b.y), f2bf(b.z), f2bf(b.w)};
    *(uint4*)(d + off*8) = *(const uint4*)r;
  }
}

// ---- prep: L = tril(pre) cast to bf16 ; layout (n,u,v) 8x512x512 ----
__global__ void mask_cast_L_kernel(const float* __restrict__ pre, u16* __restrict__ L){
  long i = (long)blockIdx.x * blockDim.x + threadIdx.x;  // chunk of 8 along v
  if (i >= 8L*512*64) return;
  int v0 = (int)(i & 63) * 8;
  int u  = (int)((i >> 6) & 511);
  float4 a = *(const float4*)(pre + i*8);
  float4 b = *(const float4*)(pre + i*8 + 4);
  float vals[8] = {a.x,a.y,a.z,a.w,b.x,b.y,b.z,b.w};
  u16 r[8];
  #pragma unroll
  for (int j=0;j<8;j++) r[j] = f2bf((v0 + j <= u) ? vals[j] : 0.0f);
  *(uint4*)(L + i*8) = *(const uint4*)r;
}

// ---- deep-pipelined NT GEMM: C[M,N] = A(MxK,rm) * B(NxK,rm)^T ----
// 256x256 tile, BK=32, 8 waves (2Mx4N), wave 128x64, acc[4+4][4] f32x4.
// 4 LDS buffers (32KB: A[256rows x 64B] + B[256rows x 64B]), stage 3 ahead,
// counted vmcnt(8), one barrier per K-tile, K-loop unrolled 4x.
// Swizzle g(r)=(r>>1)&3 on 16B chunks, both-sides (0 conflicts, verified r4).
// NO s_setprio: lockstep waves -> prio-1 MFMA clusters starve the co-resident
// wave's ds_read issue on the same SIMD (m190-class regression), serializing
// read-phase vs MFMA-phase. Without it the reader's LDS drain hides under
// the other wave's MFMA burst.
// tri: 1 = early-return blocks above the diagonal (S-gemm; output region
// provably unread downstream); 2 = Keff=row0+256 (O-gemm, A lower-tri).
// EPI: 0 bf16; 1 +bias[row] bf16; 2 tril*scale bf16; 3 +bias[col] fp32.
template<int EPI>
__global__ __launch_bounds__(512, 1)
void gemm_nt2(const u16* __restrict__ A, const u16* __restrict__ B,
              void* __restrict__ Cv, int K, int lda, int ldb, int ldc,
              long asb, long asn, long bsb, long bsn, long csb, long csn,
              const float* __restrict__ bias, float scale, int tri)
{
  extern __shared__ __align__(16) char smem[];   // 4 * 32768 = 131072 B
  const int t = threadIdx.x;
  const int lane = t & 63;
  const int wave = t >> 6;          // 0..7
  const int wm = wave >> 2;         // 0..1
  const int wn = wave & 3;          // 0..3
  const long zb = blockIdx.z >> 3, zn = blockIdx.z & 7;
  A += zb*asb + zn*asn;
  B += zb*bsb + zn*bsn;
  const int row0 = blockIdx.y * 256, col0 = blockIdx.x * 256;

  // tri=1: block entirely above the diagonal -> identically zero after mask
  // and its output region is never read downstream. Uniform exit, pre-barrier.
  if (tri == 1 && col0 >= row0 + 256) return;

  const int l15 = lane & 15, l4 = lane >> 4;

  // staging: thread t -> LDS slot t (16B), row = t>>2, chunk pos = t&3;
  // source chunk pre-swizzled: c_g = pos ^ g(row), g(r) = (r>>1)&3
  const int srow = t >> 2;                                // 0..127
  const int scol = (((t & 3) ^ ((srow >> 1) & 3)) * 8);   // elements
  const u16* gA = A + (long)(row0 + srow)*lda + scol;
  const u16* gB = B + (long)(col0 + srow)*ldb + scol;
  const long a128 = 128L*(long)lda, b128 = 128L*(long)ldb;
  const int ldst = t * 16;                                // byte slot

  // ds_read swizzled chunk: pos = l4 ^ g(row), g from l15
  const int csw = (l4 ^ ((l15 >> 1) & 3)) * 16;
  const int raw = (wm*128 + l15)*64 + csw;          // A read base (bytes)
  const int rbw = 16384 + (wn*64 + l15)*64 + csw;   // B read base

  f32x4 acc[8][4];
  #pragma unroll
  for (int m=0;m<8;m++)
    #pragma unroll
    for (int n=0;n<4;n++) acc[m][n] = (f32x4){0.f,0.f,0.f,0.f};

  int Keff = K;
  if (tri == 2) Keff = (row0 + 256 < K) ? (row0 + 256) : K;
  const int NT = Keff >> 5;   // 8 / 16 / 128 (multiple of 4)

#define STG_A(PA, BUF) \
  gload_lds16((PA),        smem + (BUF)*32768 +         ldst); \
  gload_lds16((PA) + a128, smem + (BUF)*32768 +  8192 + ldst);
#define STG_B(PB, BUF) \
  gload_lds16((PB),        smem + (BUF)*32768 + 16384 + ldst); \
  gload_lds16((PB) + b128, smem + (BUF)*32768 + 24576 + ldst);

#define WAITB(VM) \
  asm volatile("s_waitcnt vmcnt(" VM ")" ::: "memory"); \
  __builtin_amdgcn_s_barrier(); \
  asm volatile("" ::: "memory");

// Round-4-verified body (12 ds_read_b128 + 32 MFMA, no setprio) with
// stage-issue split: S1 before MFMA cluster 1, S2 between clusters.
#define COMPUTE(BUF, S1, S2) { \
  const char* base = smem + (BUF)*32768; \
  short8 bfr[4], afr[4]; \
  _Pragma("unroll") \
  for (int n=0;n<4;n++) bfr[n] = *(const short8*)(base + rbw + n*1024); \
  _Pragma("unroll") \
  for (int m=0;m<4;m++) afr[m] = *(const short8*)(base + raw + m*1024); \
  S1 \
  _Pragma("unroll") \
  for (int m=0;m<4;m++) \
    _Pragma("unroll") \
    for (int n=0;n<4;n++) \
      acc[m][n] = __builtin_amdgcn_mfma_f32_16x16x32_bf16(afr[m], bfr[n], acc[m][n],0,0,0); \
  _Pragma("unroll") \
  for (int m=0;m<4;m++) afr[m] = *(const short8*)(base + raw + (m+4)*1024); \
  S2 \
  _Pragma("unroll") \
  for (int m=0;m<4;m++) \
    _Pragma("unroll") \
    for (int n=0;n<4;n++) \
      acc[m+4][n] = __builtin_amdgcn_mfma_f32_16x16x32_bf16(afr[m], bfr[n], acc[m+4][n],0,0,0); \
}

  // prologue: 3 K-tiles in flight
  STG_A(gA,      0) STG_B(gB,      0)
  STG_A(gA + 32, 1) STG_B(gB + 32, 1)
  STG_A(gA + 64, 2) STG_B(gB + 64, 2)

  // main: tiles tk = tb..tb+3 (buffers 0..3); body(tk) stages tile tk+3
  #pragma unroll 1
  for (int tb = 0; tb < NT - 4; tb += 4){
    const u16* pa = gA + (long)(tb + 3)*32;
    const u16* pb = gB + (long)(tb + 3)*32;
    WAITB("8"); COMPUTE(0, STG_A(pa,      3), STG_B(pb,      3));
    WAITB("8"); COMPUTE(1, STG_A(pa + 32, 0), STG_B(pb + 32, 0));
    WAITB("8"); COMPUTE(2, STG_A(pa + 64, 1), STG_B(pb + 64, 1));
    WAITB("8"); COMPUTE(3, STG_A(pa + 96, 2), STG_B(pb + 96, 2));
  }
  // tail: tiles NT-4..NT-1 (buffers 0..3 since NT%4==0), one last stage
  {
    const u16* pa = gA + (long)(NT - 1)*32;
    const u16* pb = gB + (long)(NT - 1)*32;
    WAITB("8"); COMPUTE(0, STG_A(pa, 3), STG_B(pb, 3));
    WAITB("8"); COMPUTE(1, , );
    WAITB("4"); COMPUTE(2, , );
    WAITB("0"); COMPUTE(3, , );
  }
#undef STG_A
#undef STG_B
#undef WAITB
#undef COMPUTE

  // epilogue: C/D map col=lane&15, row=(lane>>4)*4+g  (HW-verified)
  if constexpr (EPI == 3){
    float* C = (float*)Cv;
    #pragma unroll
    for (int m=0;m<8;m++){
      int r0 = row0 + wm*128 + m*16 + l4*4;
      #pragma unroll
      for (int n=0;n<4;n++){
        int c = col0 + wn*64 + n*16 + l15;
        float bc = bias[c];
        #pragma unroll
        for (int g=0; g<4; g++)
          C[(long)(r0+g)*ldc + c] = acc[m][n][g] + bc;
      }
    }
  } else {
    u16* C = (u16*)Cv + zb*csb + zn*csn;
    #pragma unroll
    for (int m=0;m<8;m++){
      int r0 = row0 + wm*128 + m*16 + l4*4;
      #pragma unroll
      for (int n=0;n<4;n++){
        int c = col0 + wn*64 + n*16 + l15;
        #pragma unroll
        for (int g=0;g<4;g++){
          float v = acc[m][n][g];
          int r = r0 + g;
          if constexpr (EPI==1) v += bias[r];
          if constexpr (EPI==2) v = (c <= r) ? v*scale : 0.0f;
          C[(long)r*ldc + c] = f2bf(v);
        }
      }
    }
  }
}

// Workspace layout (bytes):
//   xb   @ 0          : 8192x4096 bf16
//   W1b  @ 67108864   : 4096x4096 bf16
//   W2b  @ 100663296  : 4096x4096 bf16
//   Lb   @ 134217728  : 8x512x512 bf16
//   Mb   @ 138412032  : 8x512x512 bf16
//   PtG  @ 142606336  : 4096x8192 bf16   PtG[c][r] = P_full[r][c]
//   MPt  @ 209715200  : 128x512x512 bf16 MPt[z][j][u] = MP[b,n,u,j]
//   Sb   @ 276824064  : 128x512x512 bf16
//   Ob   = MPt (reuse; MPt dead after S-gemm)

#define LDSB 131072

extern "C" void kernel_launch(void* const* d_in, const int* in_sizes, int n_in,
                              void* d_out, int out_size, void* d_ws, size_t ws_size,
                              hipStream_t stream)
{
  (void)in_sizes; (void)n_in; (void)out_size; (void)ws_size;
  const float* x   = (const float*)d_in[0];
  const float* W1  = (const float*)d_in[1];
  const float* b1  = (const float*)d_in[2];
  const float* pre = (const float*)d_in[3];
  const float* W2  = (const float*)d_in[4];
  const float* b2  = (const float*)d_in[5];
  float* out = (float*)d_out;
  char* ws = (char*)d_ws;

  u16* xb  = (u16*)(ws + 0L);
  u16* W1b = (u16*)(ws + 67108864L);
  u16* W2b = (u16*)(ws + 100663296L);
  u16* Lb  = (u16*)(ws + 134217728L);
  u16* Mb  = (u16*)(ws + 138412032L);
  u16* Pt  = (u16*)(ws + 142606336L);
  u16* MPt = (u16*)(ws + 209715200L);
  u16* Sb  = (u16*)(ws + 276824064L);
  u16* Ob  = MPt;  // reuse: MPt consumed by S-gemm before O-gemm writes

  hipFuncSetAttribute((const void*)gemm_nt2<0>, hipFuncAttributeMaxDynamicSharedMemorySize, LDSB);
  hipFuncSetAttribute((const void*)gemm_nt2<1>, hipFuncAttributeMaxDynamicSharedMemorySize, LDSB);
  hipFuncSetAttribute((const void*)gemm_nt2<2>, hipFuncAttributeMaxDynamicSharedMemorySize, LDSB);
  hipFuncSetAttribute((const void*)gemm_nt2<3>, hipFuncAttributeMaxDynamicSharedMemorySize, LDSB);

  // preps
  cast3_kernel<<<4096,256,0,stream>>>(x, W1, W2, xb, W1b, W2b);
  mask_cast_L_kernel<<<1024,256,0,stream>>>(pre, Lb);

  // M[n] = L[n] ·NT· L[n]          (8 batches, 512^3)
  gemm_nt2<0><<<dim3(2,2,8),512,LDSB,stream>>>(Lb, Lb, Mb, 512, 512,512,512,
      0, 262144, 0, 262144, 0, 262144, nullptr, 0.f, 0);

  // PtG = W1b ·NT· xb + b1[row]    (4096 x 8192, K=4096)
  gemm_nt2<1><<<dim3(32,16,1),512,LDSB,stream>>>(W1b, xb, Pt, 4096, 4096,4096,8192,
      0,0, 0,0, 0,0, b1, 0.f, 0);

  // MPt[z] = Pt(b,n) ·NT· M[n]     (128 batches, 512^3)
  gemm_nt2<0><<<dim3(2,2,128),512,LDSB,stream>>>(Pt, Mb, MPt, 512, 8192,512,512,
      512, 512L*8192, 0, 262144, 8L*262144, 262144, nullptr, 0.f, 0);

  // S[z] = Pt(b,n) ·NT· MPt[z], *1/sqrt(512), tril mask; skip upper blocks
  gemm_nt2<2><<<dim3(2,2,128),512,LDSB,stream>>>(Pt, MPt, Sb, 512, 8192,512,512,
      512, 512L*8192, 8L*262144, 262144, 8L*262144, 262144, nullptr, 0.04419417382f, 1);

  // O(b,n) = S[z] ·NT· Pt(b,n) -> Ob; S lower-tri => Keff = row0+256
  gemm_nt2<0><<<dim3(2,2,128),512,LDSB,stream>>>(Sb, Pt, Ob, 512, 512,8192,4096,
      8L*262144, 262144, 512, 512L*8192, 512L*4096, 512, nullptr, 0.f, 2);

  // Y = Ob ·NT· W2b + b2[col]      (8192 x 4096, K=4096, fp32 out)
  gemm_nt2<3><<<dim3(16,32,1),512,LDSB,stream>>>(Ob, W2b, out, 4096, 4096,4096,4096,
      0,0, 0,0, 0,0, b2, 0.f, 0);
}